// Round 15
// baseline (207.052 us; speedup 1.0000x reference)
//
#include <hip/hip_runtime.h>
#include <math.h>

#define NPIX 6272       // B*H*W = 2*56*56
#define LVAL 3136       // H*W
#define CIN 192         // d_inner
#define NST 16          // d_state
#define HW 56

__device__ __forceinline__ float softplusf(float v) {
    return (v > 20.0f) ? v : log1pf(expf(v));
}

// direction geometry: pixel(l) = off + i*si + j*sj, l = i*56 + j
__device__ __forceinline__ void dir_geom(int d, int b, int& si, int& sj, int& off) {
    if (d == 0)      { si = HW;  sj = 1;   off = b * LVAL; }
    else if (d == 1) { si = HW;  sj = -1;  off = b * LVAL + (HW - 1); }
    else if (d == 2) { si = 1;   sj = HW;  off = b * LVAL; }
    else             { si = -1;  sj = HW;  off = b * LVAL + (HW - 1); }
}

// K1: xz = x @ W_in ; 16 pixels/block, LDS-broadcast x, acc[16]/thread.
__global__ __launch_bounds__(384) void k_inproj(
    const float* __restrict__ x, const float* __restrict__ W_in,
    float* __restrict__ xm, float* __restrict__ z)
{
    __shared__ __align__(16) float xs[96][20];
    const int p0 = blockIdx.x * 16;
    const int t = threadIdx.x;
    for (int e = t; e < 16 * 96; e += 384) {
        int p = e / 96, kk = e % 96;
        xs[kk][p] = x[p0 * 96 + e];
    }
    __syncthreads();
    float acc[16];
#pragma unroll
    for (int p = 0; p < 16; ++p) acc[p] = 0.f;
    for (int k = 0; k < 96; ++k) {
        float w = W_in[k * 384 + t];
        float4 x0 = *(const float4*)&xs[k][0];
        float4 x1 = *(const float4*)&xs[k][4];
        float4 x2 = *(const float4*)&xs[k][8];
        float4 x3 = *(const float4*)&xs[k][12];
        acc[0]  = fmaf(x0.x, w, acc[0]);  acc[1]  = fmaf(x0.y, w, acc[1]);
        acc[2]  = fmaf(x0.z, w, acc[2]);  acc[3]  = fmaf(x0.w, w, acc[3]);
        acc[4]  = fmaf(x1.x, w, acc[4]);  acc[5]  = fmaf(x1.y, w, acc[5]);
        acc[6]  = fmaf(x1.z, w, acc[6]);  acc[7]  = fmaf(x1.w, w, acc[7]);
        acc[8]  = fmaf(x2.x, w, acc[8]);  acc[9]  = fmaf(x2.y, w, acc[9]);
        acc[10] = fmaf(x2.z, w, acc[10]); acc[11] = fmaf(x2.w, w, acc[11]);
        acc[12] = fmaf(x3.x, w, acc[12]); acc[13] = fmaf(x3.y, w, acc[13]);
        acc[14] = fmaf(x3.z, w, acc[14]); acc[15] = fmaf(x3.w, w, acc[15]);
    }
#pragma unroll
    for (int p = 0; p < 16; ++p) {
        int pix = p0 + p;
        if (t < 192) xm[pix * CIN + t] = acc[p];
        else         z[pix * CIN + (t - 192)] = acc[p];
    }
}

// K2: depthwise 3x3 conv, pad 1 — float4 over channels (4 ch/thread).
__global__ __launch_bounds__(256) void k_conv(
    const float* __restrict__ xm, const float* __restrict__ cw,
    const float* __restrict__ cb, float* __restrict__ xcv)
{
    int e = blockIdx.x * 256 + threadIdx.x;          // (pix, c-quad)
    if (e >= NPIX * (CIN / 4)) return;
    int cq = (e % (CIN / 4)) * 4;
    int pix = e / (CIN / 4);
    int w = pix % HW;
    int rest = pix / HW;
    int h = rest % HW;
    int b = rest / HW;
    float4 acc = *(const float4*)&cb[cq];
#pragma unroll
    for (int ky = 0; ky < 3; ++ky) {
        int hh = h + ky - 1;
        if (hh < 0 || hh >= HW) continue;
#pragma unroll
        for (int kx = 0; kx < 3; ++kx) {
            int ww = w + kx - 1;
            if (ww < 0 || ww >= HW) continue;
            float4 xv = *(const float4*)&xm[((b * HW + hh) * HW + ww) * CIN + cq];
            float4 wv = *(const float4*)&cw[(ky * 3 + kx) * CIN + cq];
            acc.x = fmaf(xv.x, wv.x, acc.x);
            acc.y = fmaf(xv.y, wv.y, acc.y);
            acc.z = fmaf(xv.z, wv.z, acc.z);
            acc.w = fmaf(xv.w, wv.w, acc.w);
        }
    }
    *(float4*)&xcv[pix * CIN + cq] = acc;
}

// K3: fused xproj + dt, K-SPLIT. 24 pixels/block, 512 threads = 2 k-halves
// of 96 iters each; partials combined in LDS. Phase B writes packed
// float2(dt, x) so the scan does ONE dwordx2 load per step.
__global__ __launch_bounds__(512) void k_xproj_dt(
    const float* __restrict__ xcv, const float* __restrict__ W_xproj,
    const float* __restrict__ W_dt, const float* __restrict__ b_dt,
    float* __restrict__ Bp, float* __restrict__ Cp, float2* __restrict__ dtx2)
{
    __shared__ __align__(16) float xs[192][28];
    __shared__ float part[2][24][40];
    __shared__ float dtr_lds[24][8];
    const int p0 = blockIdx.x * 24;
    const int t = threadIdx.x;
    for (int e = t; e < 24 * 192; e += 512) {
        int p = e / 192, kk = e % 192;
        int pix = p0 + p;
        xs[kk][p] = (pix < NPIX) ? xcv[pix * CIN + kk] : 0.f;
    }
    __syncthreads();
    const int th = t & 255;
    const int kh = t >> 8;               // 0..1 -> k range [kh*96, kh*96+96)
    const int j  = th % 40;
    const int pq = th / 40;              // 0..6; pq==6 idle
    if (pq < 6) {
        const int jc = (j < 38) ? j : 37;
        float a0 = 0.f, a1 = 0.f, a2 = 0.f, a3 = 0.f;
        const int k0 = kh * 96;
        for (int k = k0; k < k0 + 96; ++k) {
            float w = W_xproj[k * 38 + jc];
            float4 xv = *(const float4*)&xs[k][pq * 4];
            a0 = fmaf(xv.x, w, a0); a1 = fmaf(xv.y, w, a1);
            a2 = fmaf(xv.z, w, a2); a3 = fmaf(xv.w, w, a3);
        }
        part[kh][pq * 4 + 0][j] = a0;
        part[kh][pq * 4 + 1][j] = a1;
        part[kh][pq * 4 + 2][j] = a2;
        part[kh][pq * 4 + 3][j] = a3;
    }
    __syncthreads();
    if (kh == 0 && pq < 6 && j < 38) {
#pragma unroll
        for (int q = 0; q < 4; ++q) {
            int p = pq * 4 + q;
            float r = part[0][p][j] + part[1][p][j];
            int pix = p0 + p;
            if (j < 6) dtr_lds[p][j] = r;
            if (pix < NPIX) {
                if (j < 6)       ;   // dtr stays in LDS
                else if (j < 22) Bp[pix * NST + (j - 6)] = r;
                else             Cp[pix * NST + (j - 22)] = r;
            }
        }
    }
    __syncthreads();
    // Phase B: dt = softplus(dtr@W_dt + b_dt); pack with x from LDS.
    for (int e = t; e < 24 * 192; e += 512) {
        int p = e / 192, c = e % 192;
        int pix = p0 + p;
        if (pix >= NPIX) continue;
        float v = b_dt[c];
#pragma unroll
        for (int r = 0; r < 6; ++r)
            v = fmaf(dtr_lds[p][r], W_dt[r * CIN + c], v);
        dtx2[(size_t)pix * CIN + c] = make_float2(softplusf(v), xs[c][p]);
    }
}

// K4a pass1: n-split layout, packed (dt,x) loads. Block = 384 thr = 6 waves.
template<int CHUNK>
__global__ __launch_bounds__(384) void k_scan_p1(
    const float2* __restrict__ dtx2, const float* __restrict__ Bp,
    const float* __restrict__ A_log,
    float* __restrict__ Pbuf, float* __restrict__ qbuf)
{
    constexpr int CPR = HW / CHUNK;
    __shared__ __align__(16) float Bs[CHUNK * NST];
    const int g = blockIdx.y;
    const int k = blockIdx.x;
    const int t = threadIdx.x;
    const int wv = t >> 6;
    const int lane = t & 63;
    const int cl = lane & 31, nh = lane >> 5;
    const int c = wv * 32 + cl;
    const int n0 = nh * 8;
    const int d = g >> 1, b = g & 1;
    int si, sj, off;
    dir_geom(d, b, si, sj, off);
    const int base = off + (k / CPR) * si + ((k % CPR) * CHUNK) * sj;

    for (int e = t; e < CHUNK * NST; e += 384) {
        int jj = e >> 4, n = e & 15;
        Bs[e] = Bp[(base + jj * sj) * NST + n];
    }

    const float LOG2E = 1.4426950408889634f;
    float a2[8];
    {
        const float4* Ar = (const float4*)(A_log + c * NST + n0);
#pragma unroll
        for (int q = 0; q < 2; ++q) {
            float4 v = Ar[q];
            a2[q*4+0] = -expf(v.x) * LOG2E;
            a2[q*4+1] = -expf(v.y) * LOG2E;
            a2[q*4+2] = -expf(v.z) * LOG2E;
            a2[q*4+3] = -expf(v.w) * LOG2E;
        }
    }
    __syncthreads();

    float h[8];
#pragma unroll
    for (int i = 0; i < 8; ++i) h[i] = 0.f;
    float Sdt = 0.f;

    float2 dv = dtx2[(size_t)base * CIN + c];
    for (int jj = 0; jj < CHUNK; ++jj) {
        float dt_c = dv.x, x_c = dv.y;
        int jn = (jj + 1 < CHUNK) ? jj + 1 : jj;
        dv = dtx2[(size_t)(base + jn * sj) * CIN + c];
        float dtx = dt_c * x_c;
        Sdt += dt_c;
        float Bv[8];
        {
            const float4* Brow = (const float4*)(Bs + jj * NST + n0);
            float4 t0 = Brow[0], t1 = Brow[1];
            Bv[0]=t0.x; Bv[1]=t0.y; Bv[2]=t0.z; Bv[3]=t0.w;
            Bv[4]=t1.x; Bv[5]=t1.y; Bv[6]=t1.z; Bv[7]=t1.w;
        }
#pragma unroll
        for (int i = 0; i < 8; ++i) {
            float dA = exp2f(dt_c * a2[i]);
            h[i] = fmaf(dA, h[i], dtx * Bv[i]);
        }
    }
    float P[8];
#pragma unroll
    for (int i = 0; i < 8; ++i) P[i] = exp2f(a2[i] * Sdt);

    float4* Pd = (float4*)(Pbuf + ((size_t)(k * 8 + g) * CIN + c) * NST + n0);
    float4* qd = (float4*)(qbuf + ((size_t)(k * 8 + g) * CIN + c) * NST + n0);
    Pd[0] = make_float4(P[0], P[1], P[2], P[3]);
    Pd[1] = make_float4(P[4], P[5], P[6], P[7]);
    qd[0] = make_float4(h[0], h[1], h[2], h[3]);
    qd[1] = make_float4(h[4], h[5], h[6], h[7]);
}

// K4b: sequential chunk combine, 8-deep load pipeline (layout unchanged).
__global__ __launch_bounds__(256) void k_scan_fix(
    const float* __restrict__ Pbuf, float* __restrict__ qbuf, int nch)
{
    const int g = blockIdx.y;
    const int lo = blockIdx.x * 256 + threadIdx.x;
    const size_t stride = (size_t)8 * CIN * NST;
    size_t idx  = (size_t)g * CIN * NST + lo;
    size_t pidx = idx;
    float Pr[8], qr[8];
#pragma unroll
    for (int i = 0; i < 8; ++i) { Pr[i] = Pbuf[pidx]; qr[i] = qbuf[pidx]; pidx += stride; }
    float h = 0.f;
    for (int k = 0; k < nch; k += 8) {
        float Pn[8], qn[8];
        if (k + 8 < nch) {
#pragma unroll
            for (int i = 0; i < 8; ++i) {
                Pn[i] = Pbuf[pidx + (size_t)i * stride];
                qn[i] = qbuf[pidx + (size_t)i * stride];
            }
        } else {
#pragma unroll
            for (int i = 0; i < 8; ++i) { Pn[i] = 0.f; qn[i] = 0.f; }
        }
#pragma unroll
        for (int i = 0; i < 8; ++i) {
            qbuf[idx] = h;
            h = fmaf(Pr[i], h, qr[i]);
            idx += stride;
        }
#pragma unroll
        for (int i = 0; i < 8; ++i) { Pr[i] = Pn[i]; qr[i] = qn[i]; }
        pidx += (size_t)8 * stride;
    }
}

// K4c pass2: n-split, packed (dt,x); y halves combined via shfl_xor(32);
// nh==0 lanes add D*x and store to per-direction slab (sequence layout).
template<int CHUNK>
__global__ __launch_bounds__(384) void k_scan_p2(
    const float2* __restrict__ dtx2, const float* __restrict__ Bp,
    const float* __restrict__ Cp, const float* __restrict__ A_log,
    const float* __restrict__ D_skip,
    const float* __restrict__ qbuf, float* __restrict__ Y4)
{
    constexpr int CPR = HW / CHUNK;
    __shared__ __align__(16) float Bs[CHUNK * NST];
    __shared__ __align__(16) float Cs[CHUNK * NST];
    const int g = blockIdx.y;
    const int k = blockIdx.x;
    const int t = threadIdx.x;
    const int wv = t >> 6;
    const int lane = t & 63;
    const int cl = lane & 31, nh = lane >> 5;
    const int c = wv * 32 + cl;
    const int n0 = nh * 8;
    const int d = g >> 1, b = g & 1;
    int si, sj, off;
    dir_geom(d, b, si, sj, off);
    const int base = off + (k / CPR) * si + ((k % CPR) * CHUNK) * sj;

    for (int e = t; e < CHUNK * NST; e += 384) {
        int jj = e >> 4, n = e & 15;
        int pa = (base + jj * sj) * NST + n;
        Bs[e] = Bp[pa];
        Cs[e] = Cp[pa];
    }

    const float LOG2E = 1.4426950408889634f;
    float a2[8];
    {
        const float4* Ar = (const float4*)(A_log + c * NST + n0);
#pragma unroll
        for (int q = 0; q < 2; ++q) {
            float4 v = Ar[q];
            a2[q*4+0] = -expf(v.x) * LOG2E;
            a2[q*4+1] = -expf(v.y) * LOG2E;
            a2[q*4+2] = -expf(v.z) * LOG2E;
            a2[q*4+3] = -expf(v.w) * LOG2E;
        }
    }
    const float Dc = D_skip[c];

    float h[8];
    {
        const float4* qd = (const float4*)(qbuf + ((size_t)(k * 8 + g) * CIN + c) * NST + n0);
        float4 v0 = qd[0], v1 = qd[1];
        h[0]=v0.x; h[1]=v0.y; h[2]=v0.z; h[3]=v0.w;
        h[4]=v1.x; h[5]=v1.y; h[6]=v1.z; h[7]=v1.w;
    }
    __syncthreads();

    float* yo = Y4 + ((size_t)d * NPIX + (size_t)b * LVAL + (size_t)k * CHUNK) * CIN;

    float2 dv = dtx2[(size_t)base * CIN + c];
    for (int jj = 0; jj < CHUNK; ++jj) {
        float dt_c = dv.x, x_c = dv.y;
        int jn = (jj + 1 < CHUNK) ? jj + 1 : jj;
        dv = dtx2[(size_t)(base + jn * sj) * CIN + c];
        float dtx = dt_c * x_c;
        float Bv[8], Cv[8];
        {
            const float4* Brow = (const float4*)(Bs + jj * NST + n0);
            const float4* Crow = (const float4*)(Cs + jj * NST + n0);
            float4 t0 = Brow[0], t1 = Brow[1];
            float4 u0 = Crow[0], u1 = Crow[1];
            Bv[0]=t0.x; Bv[1]=t0.y; Bv[2]=t0.z; Bv[3]=t0.w;
            Bv[4]=t1.x; Bv[5]=t1.y; Bv[6]=t1.z; Bv[7]=t1.w;
            Cv[0]=u0.x; Cv[1]=u0.y; Cv[2]=u0.z; Cv[3]=u0.w;
            Cv[4]=u1.x; Cv[5]=u1.y; Cv[6]=u1.z; Cv[7]=u1.w;
        }
        float yc0 = 0.f, yc1 = 0.f;
#pragma unroll
        for (int i = 0; i < 8; i += 2) {
            float dA0 = exp2f(dt_c * a2[i]);
            float dA1 = exp2f(dt_c * a2[i+1]);
            h[i]   = fmaf(dA0, h[i],   dtx * Bv[i]);
            h[i+1] = fmaf(dA1, h[i+1], dtx * Bv[i+1]);
            yc0 = fmaf(h[i],   Cv[i],   yc0);
            yc1 = fmaf(h[i+1], Cv[i+1], yc1);
        }
        float yc = yc0 + yc1;
        yc += __shfl_xor(yc, 32, 64);
        if (nh == 0)
            yo[jj * CIN + c] = fmaf(Dc, x_c, yc);
    }
}

// K5: fused gate + outproj. 16 pixels/block, 384 threads, acc[4]/thread.
__global__ __launch_bounds__(384) void k_gateout(
    const float* __restrict__ Y4, const float* __restrict__ z,
    const float* __restrict__ W_out, float* __restrict__ out)
{
    __shared__ __align__(16) float xs[192][20];
    const int p0 = blockIdx.x * 16;
    const int t = threadIdx.x;
    const size_t NP = (size_t)NPIX * CIN;
    for (int e = t; e < 16 * 192; e += 384) {
        int p = e / 192, c = e % 192;
        size_t idx = (size_t)(p0 + p) * CIN + c;
        float s = Y4[idx] + Y4[idx + NP] + Y4[idx + 2 * NP] + Y4[idx + 3 * NP];
        float zz = z[idx];
        float sig = 1.f / (1.f + expf(-zz));
        xs[c][p] = zz * sig * s;
    }
    __syncthreads();
    const int j  = t % 96;
    const int ph = t / 96;          // 0..3 -> pixels ph*4 .. ph*4+3
    float acc[4] = {0.f, 0.f, 0.f, 0.f};
    for (int k = 0; k < 192; ++k) {
        float w = W_out[k * 96 + j];
        float4 xv = *(const float4*)&xs[k][ph * 4];
        acc[0] = fmaf(xv.x, w, acc[0]); acc[1] = fmaf(xv.y, w, acc[1]);
        acc[2] = fmaf(xv.z, w, acc[2]); acc[3] = fmaf(xv.w, w, acc[3]);
    }
#pragma unroll
    for (int p = 0; p < 4; ++p)
        out[(p0 + ph * 4 + p) * 96 + j] = acc[p];
}

template<int CHUNK>
static void launch_scan(const float2* dtx2, const float* Bp, const float* Cp,
                        const float* A_log, const float* D_skip,
                        float* Pbuf, float* qbuf, float* Y4, hipStream_t stream)
{
    const int nch = LVAL / CHUNK;
    k_scan_p1<CHUNK><<<dim3(nch, 8), 384, 0, stream>>>(dtx2, Bp, A_log, Pbuf, qbuf);
    k_scan_fix<<<dim3(12, 8), 256, 0, stream>>>(Pbuf, qbuf, nch);
    k_scan_p2<CHUNK><<<dim3(nch, 8), 384, 0, stream>>>(dtx2, Bp, Cp, A_log, D_skip, qbuf, Y4);
}

extern "C" void kernel_launch(void* const* d_in, const int* in_sizes, int n_in,
                              void* d_out, int out_size, void* d_ws, size_t ws_size,
                              hipStream_t stream) {
    const float* x      = (const float*)d_in[0];
    const float* W_in   = (const float*)d_in[1];
    const float* conv_w = (const float*)d_in[2];
    const float* conv_b = (const float*)d_in[3];
    const float* W_xproj= (const float*)d_in[4];
    const float* W_dt   = (const float*)d_in[5];
    const float* b_dt   = (const float*)d_in[6];
    const float* A_log  = (const float*)d_in[7];
    const float* D_skip = (const float*)d_in[8];
    const float* W_out  = (const float*)d_in[9];
    float* out = (float*)d_out;

    float* ws   = (float*)d_ws;
    float* xm   = ws;                        // [NPIX*CIN]
    float* z    = xm  + NPIX * CIN;          // [NPIX*CIN]
    float* xcv  = z   + NPIX * CIN;          // [NPIX*CIN]
    float2* dtx2= (float2*)(xcv + NPIX * CIN); // [NPIX*CIN] float2
    float* Bp   = (float*)(dtx2 + (size_t)NPIX * CIN); // [NPIX*NST]
    float* Cp   = Bp  + NPIX * NST;          // [NPIX*NST]
    float* Y4   = Cp  + NPIX * NST;          // [4*NPIX*CIN]
    float* Pbuf = Y4  + (size_t)4 * NPIX * CIN;
    // base = 11,038,720 floats (44.2 MB); carry = 2*nch*24576 floats

    const size_t base_fl = 11038720;
    const size_t ws_fl = ws_size / 4;
    // R15 A/B: CHUNK=14 (1792 blocks, 32 waves/CU offered vs 21 at c28).
    // Single-variable test vs R14's proven c28 config.
    int chunk;
    if      (ws_fl >= base_fl + (size_t)2 * 224 * 24576) chunk = 14;
    else if (ws_fl >= base_fl + (size_t)2 * 112 * 24576) chunk = 28;
    else                                                 chunk = 56;
    float* qbuf = Pbuf + (size_t)(LVAL / chunk) * 8 * CIN * NST;

    k_inproj  <<<NPIX / 16, 384, 0, stream>>>(x, W_in, xm, z);
    k_conv    <<<(NPIX * (CIN / 4)) / 256, 256, 0, stream>>>(xm, conv_w, conv_b, xcv);
    k_xproj_dt<<<(NPIX + 23) / 24, 512, 0, stream>>>(xcv, W_xproj, W_dt, b_dt, Bp, Cp, dtx2);
    if      (chunk == 14) launch_scan<14>(dtx2, Bp, Cp, A_log, D_skip, Pbuf, qbuf, Y4, stream);
    else if (chunk == 28) launch_scan<28>(dtx2, Bp, Cp, A_log, D_skip, Pbuf, qbuf, Y4, stream);
    else                  launch_scan<56>(dtx2, Bp, Cp, A_log, D_skip, Pbuf, qbuf, Y4, stream);
    k_gateout <<<NPIX / 16, 384, 0, stream>>>(Y4, z, W_out, out);
}

// Round 16
// 196.642 us; speedup vs baseline: 1.0529x; 1.0529x over previous
//
#include <hip/hip_runtime.h>
#include <math.h>

#define NPIX 6272       // B*H*W = 2*56*56
#define LVAL 3136       // H*W
#define CIN 192         // d_inner
#define NST 16          // d_state
#define HW 56

__device__ __forceinline__ float softplusf(float v) {
    return (v > 20.0f) ? v : log1pf(expf(v));
}

// direction geometry: pixel(l) = off + i*si + j*sj, l = i*56 + j
__device__ __forceinline__ void dir_geom(int d, int b, int& si, int& sj, int& off) {
    if (d == 0)      { si = HW;  sj = 1;   off = b * LVAL; }
    else if (d == 1) { si = HW;  sj = -1;  off = b * LVAL + (HW - 1); }
    else if (d == 2) { si = 1;   sj = HW;  off = b * LVAL; }
    else             { si = -1;  sj = HW;  off = b * LVAL + (HW - 1); }
}

// K1: xz = x @ W_in ; 16 pixels/block, LDS-broadcast x, acc[16]/thread.
__global__ __launch_bounds__(384) void k_inproj(
    const float* __restrict__ x, const float* __restrict__ W_in,
    float* __restrict__ xm, float* __restrict__ z)
{
    __shared__ __align__(16) float xs[96][20];
    const int p0 = blockIdx.x * 16;
    const int t = threadIdx.x;
    for (int e = t; e < 16 * 96; e += 384) {
        int p = e / 96, kk = e % 96;
        xs[kk][p] = x[p0 * 96 + e];
    }
    __syncthreads();
    float acc[16];
#pragma unroll
    for (int p = 0; p < 16; ++p) acc[p] = 0.f;
    for (int k = 0; k < 96; ++k) {
        float w = W_in[k * 384 + t];
        float4 x0 = *(const float4*)&xs[k][0];
        float4 x1 = *(const float4*)&xs[k][4];
        float4 x2 = *(const float4*)&xs[k][8];
        float4 x3 = *(const float4*)&xs[k][12];
        acc[0]  = fmaf(x0.x, w, acc[0]);  acc[1]  = fmaf(x0.y, w, acc[1]);
        acc[2]  = fmaf(x0.z, w, acc[2]);  acc[3]  = fmaf(x0.w, w, acc[3]);
        acc[4]  = fmaf(x1.x, w, acc[4]);  acc[5]  = fmaf(x1.y, w, acc[5]);
        acc[6]  = fmaf(x1.z, w, acc[6]);  acc[7]  = fmaf(x1.w, w, acc[7]);
        acc[8]  = fmaf(x2.x, w, acc[8]);  acc[9]  = fmaf(x2.y, w, acc[9]);
        acc[10] = fmaf(x2.z, w, acc[10]); acc[11] = fmaf(x2.w, w, acc[11]);
        acc[12] = fmaf(x3.x, w, acc[12]); acc[13] = fmaf(x3.y, w, acc[13]);
        acc[14] = fmaf(x3.z, w, acc[14]); acc[15] = fmaf(x3.w, w, acc[15]);
    }
#pragma unroll
    for (int p = 0; p < 16; ++p) {
        int pix = p0 + p;
        if (t < 192) xm[pix * CIN + t] = acc[p];
        else         z[pix * CIN + (t - 192)] = acc[p];
    }
}

// K2: depthwise 3x3 conv, pad 1 — float4 over channels (4 ch/thread).
__global__ __launch_bounds__(256) void k_conv(
    const float* __restrict__ xm, const float* __restrict__ cw,
    const float* __restrict__ cb, float* __restrict__ xcv)
{
    int e = blockIdx.x * 256 + threadIdx.x;          // (pix, c-quad)
    if (e >= NPIX * (CIN / 4)) return;
    int cq = (e % (CIN / 4)) * 4;
    int pix = e / (CIN / 4);
    int w = pix % HW;
    int rest = pix / HW;
    int h = rest % HW;
    int b = rest / HW;
    float4 acc = *(const float4*)&cb[cq];
#pragma unroll
    for (int ky = 0; ky < 3; ++ky) {
        int hh = h + ky - 1;
        if (hh < 0 || hh >= HW) continue;
#pragma unroll
        for (int kx = 0; kx < 3; ++kx) {
            int ww = w + kx - 1;
            if (ww < 0 || ww >= HW) continue;
            float4 xv = *(const float4*)&xm[((b * HW + hh) * HW + ww) * CIN + cq];
            float4 wv = *(const float4*)&cw[(ky * 3 + kx) * CIN + cq];
            acc.x = fmaf(xv.x, wv.x, acc.x);
            acc.y = fmaf(xv.y, wv.y, acc.y);
            acc.z = fmaf(xv.z, wv.z, acc.z);
            acc.w = fmaf(xv.w, wv.w, acc.w);
        }
    }
    *(float4*)&xcv[pix * CIN + cq] = acc;
}

// K3: fused xproj + dt, K-SPLIT. 24 pixels/block, 512 threads = 2 k-halves
// of 96 iters each; partials combined in LDS. Phase B writes packed
// float2(dt, x) so the scan does ONE dwordx2 load per step.
__global__ __launch_bounds__(512) void k_xproj_dt(
    const float* __restrict__ xcv, const float* __restrict__ W_xproj,
    const float* __restrict__ W_dt, const float* __restrict__ b_dt,
    float* __restrict__ Bp, float* __restrict__ Cp, float2* __restrict__ dtx2)
{
    __shared__ __align__(16) float xs[192][28];
    __shared__ float part[2][24][40];
    __shared__ float dtr_lds[24][8];
    const int p0 = blockIdx.x * 24;
    const int t = threadIdx.x;
    for (int e = t; e < 24 * 192; e += 512) {
        int p = e / 192, kk = e % 192;
        int pix = p0 + p;
        xs[kk][p] = (pix < NPIX) ? xcv[pix * CIN + kk] : 0.f;
    }
    __syncthreads();
    const int th = t & 255;
    const int kh = t >> 8;               // 0..1 -> k range [kh*96, kh*96+96)
    const int j  = th % 40;
    const int pq = th / 40;              // 0..6; pq==6 idle
    if (pq < 6) {
        const int jc = (j < 38) ? j : 37;
        float a0 = 0.f, a1 = 0.f, a2 = 0.f, a3 = 0.f;
        const int k0 = kh * 96;
        for (int k = k0; k < k0 + 96; ++k) {
            float w = W_xproj[k * 38 + jc];
            float4 xv = *(const float4*)&xs[k][pq * 4];
            a0 = fmaf(xv.x, w, a0); a1 = fmaf(xv.y, w, a1);
            a2 = fmaf(xv.z, w, a2); a3 = fmaf(xv.w, w, a3);
        }
        part[kh][pq * 4 + 0][j] = a0;
        part[kh][pq * 4 + 1][j] = a1;
        part[kh][pq * 4 + 2][j] = a2;
        part[kh][pq * 4 + 3][j] = a3;
    }
    __syncthreads();
    if (kh == 0 && pq < 6 && j < 38) {
#pragma unroll
        for (int q = 0; q < 4; ++q) {
            int p = pq * 4 + q;
            float r = part[0][p][j] + part[1][p][j];
            int pix = p0 + p;
            if (j < 6) dtr_lds[p][j] = r;
            if (pix < NPIX) {
                if (j < 6)       ;   // dtr stays in LDS
                else if (j < 22) Bp[pix * NST + (j - 6)] = r;
                else             Cp[pix * NST + (j - 22)] = r;
            }
        }
    }
    __syncthreads();
    // Phase B: dt = softplus(dtr@W_dt + b_dt); pack with x from LDS.
    for (int e = t; e < 24 * 192; e += 512) {
        int p = e / 192, c = e % 192;
        int pix = p0 + p;
        if (pix >= NPIX) continue;
        float v = b_dt[c];
#pragma unroll
        for (int r = 0; r < 6; ++r)
            v = fmaf(dtr_lds[p][r], W_dt[r * CIN + c], v);
        dtx2[(size_t)pix * CIN + c] = make_float2(softplusf(v), xs[c][p]);
    }
}

// K4a pass1: n-split layout, packed (dt,x) loads. Block = 384 thr = 6 waves.
template<int CHUNK>
__global__ __launch_bounds__(384) void k_scan_p1(
    const float2* __restrict__ dtx2, const float* __restrict__ Bp,
    const float* __restrict__ A_log,
    float* __restrict__ Pbuf, float* __restrict__ qbuf)
{
    constexpr int CPR = HW / CHUNK;
    __shared__ __align__(16) float Bs[CHUNK * NST];
    const int g = blockIdx.y;
    const int k = blockIdx.x;
    const int t = threadIdx.x;
    const int wv = t >> 6;
    const int lane = t & 63;
    const int cl = lane & 31, nh = lane >> 5;
    const int c = wv * 32 + cl;
    const int n0 = nh * 8;
    const int d = g >> 1, b = g & 1;
    int si, sj, off;
    dir_geom(d, b, si, sj, off);
    const int base = off + (k / CPR) * si + ((k % CPR) * CHUNK) * sj;

    for (int e = t; e < CHUNK * NST; e += 384) {
        int jj = e >> 4, n = e & 15;
        Bs[e] = Bp[(base + jj * sj) * NST + n];
    }

    const float LOG2E = 1.4426950408889634f;
    float a2[8];
    {
        const float4* Ar = (const float4*)(A_log + c * NST + n0);
#pragma unroll
        for (int q = 0; q < 2; ++q) {
            float4 v = Ar[q];
            a2[q*4+0] = -expf(v.x) * LOG2E;
            a2[q*4+1] = -expf(v.y) * LOG2E;
            a2[q*4+2] = -expf(v.z) * LOG2E;
            a2[q*4+3] = -expf(v.w) * LOG2E;
        }
    }
    __syncthreads();

    float h[8];
#pragma unroll
    for (int i = 0; i < 8; ++i) h[i] = 0.f;
    float Sdt = 0.f;

    float2 dv = dtx2[(size_t)base * CIN + c];
    for (int jj = 0; jj < CHUNK; ++jj) {
        float dt_c = dv.x, x_c = dv.y;
        int jn = (jj + 1 < CHUNK) ? jj + 1 : jj;
        dv = dtx2[(size_t)(base + jn * sj) * CIN + c];
        float dtx = dt_c * x_c;
        Sdt += dt_c;
        float Bv[8];
        {
            const float4* Brow = (const float4*)(Bs + jj * NST + n0);
            float4 t0 = Brow[0], t1 = Brow[1];
            Bv[0]=t0.x; Bv[1]=t0.y; Bv[2]=t0.z; Bv[3]=t0.w;
            Bv[4]=t1.x; Bv[5]=t1.y; Bv[6]=t1.z; Bv[7]=t1.w;
        }
#pragma unroll
        for (int i = 0; i < 8; ++i) {
            float dA = exp2f(dt_c * a2[i]);
            h[i] = fmaf(dA, h[i], dtx * Bv[i]);
        }
    }
    float P[8];
#pragma unroll
    for (int i = 0; i < 8; ++i) P[i] = exp2f(a2[i] * Sdt);

    float4* Pd = (float4*)(Pbuf + ((size_t)(k * 8 + g) * CIN + c) * NST + n0);
    float4* qd = (float4*)(qbuf + ((size_t)(k * 8 + g) * CIN + c) * NST + n0);
    Pd[0] = make_float4(P[0], P[1], P[2], P[3]);
    Pd[1] = make_float4(P[4], P[5], P[6], P[7]);
    qd[0] = make_float4(h[0], h[1], h[2], h[3]);
    qd[1] = make_float4(h[4], h[5], h[6], h[7]);
}

// K4b: sequential chunk combine, 8-deep load pipeline (layout unchanged).
__global__ __launch_bounds__(256) void k_scan_fix(
    const float* __restrict__ Pbuf, float* __restrict__ qbuf, int nch)
{
    const int g = blockIdx.y;
    const int lo = blockIdx.x * 256 + threadIdx.x;
    const size_t stride = (size_t)8 * CIN * NST;
    size_t idx  = (size_t)g * CIN * NST + lo;
    size_t pidx = idx;
    float Pr[8], qr[8];
#pragma unroll
    for (int i = 0; i < 8; ++i) { Pr[i] = Pbuf[pidx]; qr[i] = qbuf[pidx]; pidx += stride; }
    float h = 0.f;
    for (int k = 0; k < nch; k += 8) {
        float Pn[8], qn[8];
        if (k + 8 < nch) {
#pragma unroll
            for (int i = 0; i < 8; ++i) {
                Pn[i] = Pbuf[pidx + (size_t)i * stride];
                qn[i] = qbuf[pidx + (size_t)i * stride];
            }
        } else {
#pragma unroll
            for (int i = 0; i < 8; ++i) { Pn[i] = 0.f; qn[i] = 0.f; }
        }
#pragma unroll
        for (int i = 0; i < 8; ++i) {
            qbuf[idx] = h;
            h = fmaf(Pr[i], h, qr[i]);
            idx += stride;
        }
#pragma unroll
        for (int i = 0; i < 8; ++i) { Pr[i] = Pn[i]; qr[i] = qn[i]; }
        pidx += (size_t)8 * stride;
    }
}

// K4c pass2: n-split, packed (dt,x); y halves combined via shfl_xor(32);
// nh==0 lanes add D*x and store to per-direction slab (sequence layout).
template<int CHUNK>
__global__ __launch_bounds__(384) void k_scan_p2(
    const float2* __restrict__ dtx2, const float* __restrict__ Bp,
    const float* __restrict__ Cp, const float* __restrict__ A_log,
    const float* __restrict__ D_skip,
    const float* __restrict__ qbuf, float* __restrict__ Y4)
{
    constexpr int CPR = HW / CHUNK;
    __shared__ __align__(16) float Bs[CHUNK * NST];
    __shared__ __align__(16) float Cs[CHUNK * NST];
    const int g = blockIdx.y;
    const int k = blockIdx.x;
    const int t = threadIdx.x;
    const int wv = t >> 6;
    const int lane = t & 63;
    const int cl = lane & 31, nh = lane >> 5;
    const int c = wv * 32 + cl;
    const int n0 = nh * 8;
    const int d = g >> 1, b = g & 1;
    int si, sj, off;
    dir_geom(d, b, si, sj, off);
    const int base = off + (k / CPR) * si + ((k % CPR) * CHUNK) * sj;

    for (int e = t; e < CHUNK * NST; e += 384) {
        int jj = e >> 4, n = e & 15;
        int pa = (base + jj * sj) * NST + n;
        Bs[e] = Bp[pa];
        Cs[e] = Cp[pa];
    }

    const float LOG2E = 1.4426950408889634f;
    float a2[8];
    {
        const float4* Ar = (const float4*)(A_log + c * NST + n0);
#pragma unroll
        for (int q = 0; q < 2; ++q) {
            float4 v = Ar[q];
            a2[q*4+0] = -expf(v.x) * LOG2E;
            a2[q*4+1] = -expf(v.y) * LOG2E;
            a2[q*4+2] = -expf(v.z) * LOG2E;
            a2[q*4+3] = -expf(v.w) * LOG2E;
        }
    }
    const float Dc = D_skip[c];

    float h[8];
    {
        const float4* qd = (const float4*)(qbuf + ((size_t)(k * 8 + g) * CIN + c) * NST + n0);
        float4 v0 = qd[0], v1 = qd[1];
        h[0]=v0.x; h[1]=v0.y; h[2]=v0.z; h[3]=v0.w;
        h[4]=v1.x; h[5]=v1.y; h[6]=v1.z; h[7]=v1.w;
    }
    __syncthreads();

    float* yo = Y4 + ((size_t)d * NPIX + (size_t)b * LVAL + (size_t)k * CHUNK) * CIN;

    float2 dv = dtx2[(size_t)base * CIN + c];
    for (int jj = 0; jj < CHUNK; ++jj) {
        float dt_c = dv.x, x_c = dv.y;
        int jn = (jj + 1 < CHUNK) ? jj + 1 : jj;
        dv = dtx2[(size_t)(base + jn * sj) * CIN + c];
        float dtx = dt_c * x_c;
        float Bv[8], Cv[8];
        {
            const float4* Brow = (const float4*)(Bs + jj * NST + n0);
            const float4* Crow = (const float4*)(Cs + jj * NST + n0);
            float4 t0 = Brow[0], t1 = Brow[1];
            float4 u0 = Crow[0], u1 = Crow[1];
            Bv[0]=t0.x; Bv[1]=t0.y; Bv[2]=t0.z; Bv[3]=t0.w;
            Bv[4]=t1.x; Bv[5]=t1.y; Bv[6]=t1.z; Bv[7]=t1.w;
            Cv[0]=u0.x; Cv[1]=u0.y; Cv[2]=u0.z; Cv[3]=u0.w;
            Cv[4]=u1.x; Cv[5]=u1.y; Cv[6]=u1.z; Cv[7]=u1.w;
        }
        float yc0 = 0.f, yc1 = 0.f;
#pragma unroll
        for (int i = 0; i < 8; i += 2) {
            float dA0 = exp2f(dt_c * a2[i]);
            float dA1 = exp2f(dt_c * a2[i+1]);
            h[i]   = fmaf(dA0, h[i],   dtx * Bv[i]);
            h[i+1] = fmaf(dA1, h[i+1], dtx * Bv[i+1]);
            yc0 = fmaf(h[i],   Cv[i],   yc0);
            yc1 = fmaf(h[i+1], Cv[i+1], yc1);
        }
        float yc = yc0 + yc1;
        yc += __shfl_xor(yc, 32, 64);
        if (nh == 0)
            yo[jj * CIN + c] = fmaf(Dc, x_c, yc);
    }
}

// K5: fused gate + outproj. 16 pixels/block, 384 threads, acc[4]/thread.
__global__ __launch_bounds__(384) void k_gateout(
    const float* __restrict__ Y4, const float* __restrict__ z,
    const float* __restrict__ W_out, float* __restrict__ out)
{
    __shared__ __align__(16) float xs[192][20];
    const int p0 = blockIdx.x * 16;
    const int t = threadIdx.x;
    const size_t NP = (size_t)NPIX * CIN;
    for (int e = t; e < 16 * 192; e += 384) {
        int p = e / 192, c = e % 192;
        size_t idx = (size_t)(p0 + p) * CIN + c;
        float s = Y4[idx] + Y4[idx + NP] + Y4[idx + 2 * NP] + Y4[idx + 3 * NP];
        float zz = z[idx];
        float sig = 1.f / (1.f + expf(-zz));
        xs[c][p] = zz * sig * s;
    }
    __syncthreads();
    const int j  = t % 96;
    const int ph = t / 96;          // 0..3 -> pixels ph*4 .. ph*4+3
    float acc[4] = {0.f, 0.f, 0.f, 0.f};
    for (int k = 0; k < 192; ++k) {
        float w = W_out[k * 96 + j];
        float4 xv = *(const float4*)&xs[k][ph * 4];
        acc[0] = fmaf(xv.x, w, acc[0]); acc[1] = fmaf(xv.y, w, acc[1]);
        acc[2] = fmaf(xv.z, w, acc[2]); acc[3] = fmaf(xv.w, w, acc[3]);
    }
#pragma unroll
    for (int p = 0; p < 4; ++p)
        out[(p0 + ph * 4 + p) * 96 + j] = acc[p];
}

template<int CHUNK>
static void launch_scan(const float2* dtx2, const float* Bp, const float* Cp,
                        const float* A_log, const float* D_skip,
                        float* Pbuf, float* qbuf, float* Y4, hipStream_t stream)
{
    const int nch = LVAL / CHUNK;
    k_scan_p1<CHUNK><<<dim3(nch, 8), 384, 0, stream>>>(dtx2, Bp, A_log, Pbuf, qbuf);
    k_scan_fix<<<dim3(12, 8), 256, 0, stream>>>(Pbuf, qbuf, nch);
    k_scan_p2<CHUNK><<<dim3(nch, 8), 384, 0, stream>>>(dtx2, Bp, Cp, A_log, D_skip, qbuf, Y4);
}

extern "C" void kernel_launch(void* const* d_in, const int* in_sizes, int n_in,
                              void* d_out, int out_size, void* d_ws, size_t ws_size,
                              hipStream_t stream) {
    const float* x      = (const float*)d_in[0];
    const float* W_in   = (const float*)d_in[1];
    const float* conv_w = (const float*)d_in[2];
    const float* conv_b = (const float*)d_in[3];
    const float* W_xproj= (const float*)d_in[4];
    const float* W_dt   = (const float*)d_in[5];
    const float* b_dt   = (const float*)d_in[6];
    const float* A_log  = (const float*)d_in[7];
    const float* D_skip = (const float*)d_in[8];
    const float* W_out  = (const float*)d_in[9];
    float* out = (float*)d_out;

    float* ws   = (float*)d_ws;
    float* xm   = ws;                        // [NPIX*CIN]
    float* z    = xm  + NPIX * CIN;          // [NPIX*CIN]
    float* xcv  = z   + NPIX * CIN;          // [NPIX*CIN]
    float2* dtx2= (float2*)(xcv + NPIX * CIN); // [NPIX*CIN] float2
    float* Bp   = (float*)(dtx2 + (size_t)NPIX * CIN); // [NPIX*NST]
    float* Cp   = Bp  + NPIX * NST;          // [NPIX*NST]
    float* Y4   = Cp  + NPIX * NST;          // [4*NPIX*CIN]
    float* Pbuf = Y4  + (size_t)4 * NPIX * CIN;
    // base = 11,038,720 floats (44.2 MB); carry = 2*nch*24576 floats

    const size_t base_fl = 11038720;
    const size_t ws_fl = ws_size / 4;
    // CHUNK=28: verified optimum (R15 single-variable A/B: c14=207us, c28=197us;
    // c56=265us from R5). Occupancy/carry-traffic sweet spot.
    int chunk;
    if (ws_fl >= base_fl + (size_t)2 * 112 * 24576) chunk = 28;
    else                                            chunk = 56;
    float* qbuf = Pbuf + (size_t)(LVAL / chunk) * 8 * CIN * NST;

    k_inproj  <<<NPIX / 16, 384, 0, stream>>>(x, W_in, xm, z);
    k_conv    <<<(NPIX * (CIN / 4)) / 256, 256, 0, stream>>>(xm, conv_w, conv_b, xcv);
    k_xproj_dt<<<(NPIX + 23) / 24, 512, 0, stream>>>(xcv, W_xproj, W_dt, b_dt, Bp, Cp, dtx2);
    if (chunk == 28) launch_scan<28>(dtx2, Bp, Cp, A_log, D_skip, Pbuf, qbuf, Y4, stream);
    else             launch_scan<56>(dtx2, Bp, Cp, A_log, D_skip, Pbuf, qbuf, Y4, stream);
    k_gateout <<<NPIX / 16, 384, 0, stream>>>(Y4, z, W_out, out);
}